// Round 1
// 376.993 us; speedup vs baseline: 1.0285x; 1.0285x over previous
//
#include <hip/hip_runtime.h>
#include <math.h>

typedef __bf16 bf16x8 __attribute__((ext_vector_type(8)));
typedef __bf16 bf16x4 __attribute__((ext_vector_type(4)));
typedef float f32x4 __attribute__((ext_vector_type(4)));

#define HD 1024
#define SEQ 2048
#define NB 4
#define WEL (HD * HD)   // elements per weight matrix

// Load 8 contiguous elements as bf16x8, converting f32 -> bf16 if needed.
__device__ inline bf16x8 load8cvt(const __bf16* p) { return *(const bf16x8*)p; }
__device__ inline bf16x8 load8cvt(const float* p) {
    f32x4 a = *(const f32x4*)p;
    f32x4 b = *(const f32x4*)(p + 4);
    bf16x8 r;
#pragma unroll
    for (int i = 0; i < 4; ++i) { r[i] = (__bf16)a[i]; r[i + 4] = (__bf16)b[i]; }
    return r;
}

// Load 4 contiguous elements as f32x4 (from f32 or bf16 source).
__device__ inline f32x4 load4f(const float* p) { return *(const f32x4*)p; }
__device__ inline f32x4 load4f(const __bf16* p) {
    bf16x4 v = *(const bf16x4*)p;
    f32x4 r;
#pragma unroll
    for (int i = 0; i < 4; ++i) r[i] = (float)v[i];
    return r;
}

// Async global->LDS, 16 bytes per lane (global_load_lds_dwordx4).
__device__ inline void gld_lds16(const void* g, void* l) {
    __builtin_amdgcn_global_load_lds(
        (const __attribute__((address_space(1))) unsigned int*)g,
        (__attribute__((address_space(3))) unsigned int*)l, 16, 0, 0);
}

// ---------------------------------------------------------------------------
// XOR-swizzled LDS tile: logical [128 rows][8 chunks of 8 bf16].
// LDS chunk (row, j) holds GLOBAL chunk (row, j ^ (row&7)). This breaks the
// 128B-row-stride bank aliasing while keeping the LDS destination linear, as
// required by global_load_lds (wave-base + lane*16, no scatter).
// ---------------------------------------------------------------------------
template <typename T>
__device__ inline void stage_tile(const T* __restrict__ G, int ld, __bf16* s, int tid)
{
    const int r  = tid >> 3;                          // 0..31
    const int co = ((tid & 7) ^ (r & 7)) * 8;         // swizzled source column
    if constexpr (sizeof(T) == 2) {
        __bf16* dst = s + (tid >> 6) * 512;           // wave-uniform base
#pragma unroll
        for (int c = 0; c < 4; ++c)
            gld_lds16(G + (long)(c * 32 + r) * ld + co, dst + c * 2048);
    } else {
#pragma unroll
        for (int c = 0; c < 4; ++c)
            *(bf16x8*)(s + c * 2048 + tid * 8) = load8cvt(G + (long)(c * 32 + r) * ld + co);
    }
}

// Read global chunk (row, c) from the swizzled tile.
__device__ inline bf16x8 frag_read(const __bf16* s, int row, int c)
{
    return *(const bf16x8*)&s[row * 64 + ((c ^ (row & 7)) * 8)];
}

// Compute one BK=64 tile from staged sA/sB into acc (4x4 frags / wave).
__device__ inline void mfma_ktile(const __bf16* __restrict__ sa,
                                  const __bf16* __restrict__ sb,
                                  int wm, int wn, int l15, int quad,
                                  f32x4 (&acc)[4][4])
{
#pragma unroll
    for (int kk = 0; kk < 64; kk += 32) {
        const int c8 = quad + (kk >> 3);
        bf16x8 af[4], bf[4];
#pragma unroll
        for (int i = 0; i < 4; ++i)
            af[i] = frag_read(sa, wm + i * 16 + l15, c8);
#pragma unroll
        for (int j = 0; j < 4; ++j)
            bf[j] = frag_read(sb, wn + j * 16 + l15, c8);
#pragma unroll
        for (int i = 0; i < 4; ++i)
#pragma unroll
            for (int j = 0; j < 4; ++j)
                acc[i][j] = __builtin_amdgcn_mfma_f32_16x16x32_bf16(af[i], bf[j], acc[i][j], 0, 0, 0);
    }
}

// ---------------------------------------------------------------------------
// Z-batched projection GEMM (see previous round). Now double-buffered:
// stage K-tile t+1 BEFORE computing tile t, single __syncthreads per tile,
// so the vmcnt(0) drain at the barrier lands after ~350cy of ds_read+MFMA
// instead of fully exposing HBM/L2 latency (measured MfmaUtil was 19.5%).
// ---------------------------------------------------------------------------
struct Proj3 {
    const void* A[3];
    const void* W[3];
    const float* bias[3];
    __bf16* C[3];
    int vtmask;
};

template <typename TA, typename TW>
__global__ __launch_bounds__(256) void gemm_proj(Proj3 p)
{
    __shared__ __bf16 sA[2][128 * 64];
    __shared__ __bf16 sB[2][128 * 64];

    const int tid = threadIdx.x;
    const int L = blockIdx.x;
    const int per = gridDim.x >> 3;
    const int wrk = (L & 7) * per + (L >> 3);
    const int n0 = (wrk & 7) * 128;
    const int m0 = ((wrk >> 3) & 63) * 128;
    const int z  = wrk >> 9;
    const bool vt = (p.vtmask >> z) & 1;

    const TA* Ag = (const TA*)p.A[z] + (long)m0 * HD;
    const TW* Wg = (const TW*)p.W[z] + (long)n0 * HD;
    const float* bias = p.bias[z];
    __bf16* C = p.C[z];

    const int lane = tid & 63;
    const int l15  = lane & 15;
    const int quad = lane >> 4;
    const int wave = tid >> 6;
    const int wm = (wave >> 1) * 64;
    const int wn = (wave & 1) * 64;

    f32x4 acc[4][4];
    const f32x4 zero = {0.f, 0.f, 0.f, 0.f};
#pragma unroll
    for (int i = 0; i < 4; ++i)
#pragma unroll
        for (int j = 0; j < 4; ++j) acc[i][j] = zero;

    // prologue: stage tile 0
    stage_tile(Ag, HD, sA[0], tid);
    stage_tile(Wg, HD, sB[0], tid);
    __syncthreads();

    int cur = 0;
    for (int kc = 0; kc < HD; kc += 64) {
        const int nxt = kc + 64;
        if (nxt < HD) {                       // issue next tile's loads first
            stage_tile(Ag + nxt, HD, sA[cur ^ 1], tid);
            stage_tile(Wg + nxt, HD, sB[cur ^ 1], tid);
        }
        mfma_ktile(sA[cur], sB[cur], wm, wn, l15, quad, acc);
        __syncthreads();                      // drains vmcnt after compute
        cur ^= 1;
    }

#pragma unroll
    for (int j = 0; j < 4; ++j) {
        const int col = n0 + wn + j * 16 + l15;
        const float bv = bias[col];
#pragma unroll
        for (int i = 0; i < 4; ++i) {
#pragma unroll
            for (int r = 0; r < 4; ++r) {
                const int row = m0 + wm + i * 16 + quad * 4 + r;
                const float v = acc[i][j][r] + bv;
                if (vt) {
                    C[(((long)(row >> 11) * HD) + col) * SEQ + (row & (SEQ - 1))] = (__bf16)v;
                } else {
                    C[(long)row * HD + col] = (__bf16)v;
                }
            }
        }
    }
}

// ---------------------------------------------------------------------------
// GEMM (B-transposed), same double-buffered prefetch pipeline.
// TRI:   1-D grid 544 = 4 batches x 136 causal (s<=t) 128x128 blocks.
// !TRI:  context GEMM, 1-D grid 512 = 4 batches x (8 n x 16 m).
// CKLIM: causal context (m=t,k=s): A rows zero for s>t -> Kend = m0+128.
// EXPSUM: epilogue stores e=exp(alpha*v) and accumulates per-column sums of e
//         over valid rows (row<=col) into gsum[col] (LDS then global atomics).
// ---------------------------------------------------------------------------
template <bool TRI, bool CKLIM, bool EXPSUM, typename OutT>
__global__ __launch_bounds__(256) void gemm_bt(
    const __bf16* __restrict__ A, long strideA, int lda,
    const __bf16* __restrict__ B, long strideB, int ldb,
    OutT* __restrict__ C, long strideC, int ldc,
    float* __restrict__ gsum,
    int K, float alpha)
{
    __shared__ __bf16 sA[2][128 * 64];
    __shared__ __bf16 sB[2][128 * 64];
    __shared__ float csum[128];

    const int tid = threadIdx.x;
    const int L = blockIdx.x;
    const int per = gridDim.x >> 3;
    const int wrk = (L & 7) * per + (L >> 3);
    int n0, m0, z;
    if (TRI) {
        const int Lt = wrk % 136;
        z = wrk / 136;
        int tb = (int)((sqrtf(8.f * Lt + 1.f) - 1.f) * 0.5f);
        while ((tb + 1) * (tb + 2) / 2 <= Lt) ++tb;
        while (tb * (tb + 1) / 2 > Lt) --tb;
        const int sb = Lt - tb * (tb + 1) / 2;
        n0 = tb * 128;      // t-block (column)
        m0 = sb * 128;      // s-block (row), sb <= tb
    } else {
        n0 = (wrk & 7) * 128;
        m0 = ((wrk >> 3) & 15) * 128;
        z  = wrk >> 7;
    }

    const __bf16* Ag = A + (long)z * strideA + (long)m0 * lda;
    const __bf16* Bg = B + (long)z * strideB + (long)n0 * ldb;
    C += (long)z * strideC;
    if (EXPSUM) {
        gsum += (long)z * SEQ;
        if (tid < 128) csum[tid] = 0.f;   // visible after first __syncthreads
    }

    const int lane = tid & 63;
    const int l15  = lane & 15;
    const int quad = lane >> 4;
    const int wave = tid >> 6;
    const int wm = (wave >> 1) * 64;
    const int wn = (wave & 1) * 64;

    f32x4 acc[4][4];
    const f32x4 zero = {0.f, 0.f, 0.f, 0.f};
#pragma unroll
    for (int i = 0; i < 4; ++i)
#pragma unroll
        for (int j = 0; j < 4; ++j) acc[i][j] = zero;

    const int Kend = CKLIM ? min(K, m0 + 128) : K;

    // prologue: stage tile 0
    stage_tile(Ag, lda, sA[0], tid);
    stage_tile(Bg, ldb, sB[0], tid);
    __syncthreads();

    int cur = 0;
    for (int kc = 0; kc < Kend; kc += 64) {
        const int nxt = kc + 64;
        if (nxt < Kend) {                     // issue next tile's loads first
            stage_tile(Ag + nxt, lda, sA[cur ^ 1], tid);
            stage_tile(Bg + nxt, ldb, sB[cur ^ 1], tid);
        }
        mfma_ktile(sA[cur], sB[cur], wm, wn, l15, quad, acc);
        __syncthreads();                      // drains vmcnt after compute
        cur ^= 1;
    }

#pragma unroll
    for (int j = 0; j < 4; ++j) {
        const int col = n0 + wn + j * 16 + l15;
        float part = 0.f;
#pragma unroll
        for (int i = 0; i < 4; ++i) {
#pragma unroll
            for (int r = 0; r < 4; ++r) {
                const int row = m0 + wm + i * 16 + quad * 4 + r;
                float v = acc[i][j][r] * alpha;
                if (EXPSUM) {
                    v = __expf(v);
                    if (row <= col) part += v;
                }
                C[(long)row * ldc + col] = (OutT)v;
            }
        }
        if (EXPSUM) atomicAdd(&csum[wn + j * 16 + l15], part);
    }
    if (EXPSUM) {
        __syncthreads();
        if (tid < 128) atomicAdd(&gsum[n0 + tid], csum[tid]);
    }
}

// ---------------------------------------------------------------------------
// Scale + emit: E[b][s][t] (unnormalized exp, dtype ET) ->
//   attn[b][s][t] f32 = (s<=t ? E*inv[t] : 0)   (final output, outAttn)
//   attnT[b][t][s] bf16 (context GEMM input; only tiles with s0<=t0+127,
//   others never read thanks to CKLIM)
// 128x128 tile per block as 2x2 64x64 sub-tiles through a padded LDS tile.
// ---------------------------------------------------------------------------
template <typename ET>
__global__ __launch_bounds__(256) void scale_emit(
    const ET* __restrict__ E, float* __restrict__ Out,
    const float* __restrict__ csum, __bf16* __restrict__ AT)
{
    __shared__ __bf16 tile[64][65];
    const int b = blockIdx.z;
    const int t0 = blockIdx.x * 128;
    const int s0 = blockIdx.y * 128;
    const ET* Eb = E + (long)b * SEQ * SEQ;
    float* Ob = Out + (long)b * SEQ * SEQ;
    __bf16* Ab = AT + (long)b * SEQ * SEQ;
    const int tid = threadIdx.x;

    if (s0 > t0 + 127) {   // fully masked: f32 zeros only (attnT never read)
        const f32x4 z4 = {0.f, 0.f, 0.f, 0.f};
        const int c4 = (tid & 31) * 4;
        for (int r = tid >> 5; r < 128; r += 8)
            *(f32x4*)&Ob[(long)(s0 + r) * SEQ + t0 + c4] = z4;
        return;
    }

#pragma unroll
    for (int ds = 0; ds < 2; ++ds) {
#pragma unroll
        for (int dt = 0; dt < 2; ++dt) {
            const int ss = s0 + ds * 64, tt = t0 + dt * 64;
            const int c4 = (tid & 15) * 4;
            const int tcol = tt + c4;
            const f32x4 sv = *(const f32x4*)&csum[(long)b * SEQ + tcol];
            f32x4 inv;
#pragma unroll
            for (int k = 0; k < 4; ++k) inv[k] = 1.0f / sv[k];
#pragma unroll
            for (int r0 = 0; r0 < 64; r0 += 16) {
                const int s = ss + r0 + (tid >> 4);
                f32x4 e = load4f(&Eb[(long)s * SEQ + tcol]);
                f32x4 p;
#pragma unroll
                for (int k = 0; k < 4; ++k)
                    p[k] = (s <= tcol + k) ? e[k] * inv[k] : 0.f;
                *(f32x4*)&Ob[(long)s * SEQ + tcol] = p;
#pragma unroll
                for (int k = 0; k < 4; ++k)
                    tile[r0 + (tid >> 4)][c4 + k] = (__bf16)p[k];
            }
            __syncthreads();
            const int tr = tid >> 2;                  // 0..63
            const int sc = (tid & 3) * 16;            // 0,16,32,48
            __bf16 v[16];
#pragma unroll
            for (int jj = 0; jj < 16; ++jj) v[jj] = tile[sc + jj][tr];
            *(bf16x8*)&Ab[(long)(tt + tr) * SEQ + ss + sc]     = *(bf16x8*)v;
            *(bf16x8*)&Ab[(long)(tt + tr) * SEQ + ss + sc + 8] = *(bf16x8*)(v + 8);
            __syncthreads();
        }
    }
}

// ---------------------------------------------------------------------------
// Batched f32 -> bf16 convert: up to 6 jobs in one dispatch.
// ---------------------------------------------------------------------------
struct CvtJob { const float* in; __bf16* out; int nblk; };
struct Cvt6 { CvtJob j[6]; };
__global__ __launch_bounds__(256) void cvt_bf16(Cvt6 c)
{
    const CvtJob jb = c.j[blockIdx.y];
    if ((int)blockIdx.x >= jb.nblk) return;
    const long i = ((long)blockIdx.x * 256 + threadIdx.x) * 8;
    *(bf16x8*)&jb.out[i] = load8cvt(&jb.in[i]);
}

// ---------------------------------------------------------------------------
extern "C" void kernel_launch(void* const* d_in, const int* in_sizes, int n_in,
                              void* d_out, int out_size, void* d_ws, size_t ws_size,
                              hipStream_t stream)
{
    const float* queries = (const float*)d_in[0];
    const float* keys    = (const float*)d_in[1];
    const float* values  = (const float*)d_in[2];
    const float* Wq = (const float*)d_in[3];
    const float* bq = (const float*)d_in[4];
    const float* Wk = (const float*)d_in[5];
    const float* bk = (const float*)d_in[6];
    const float* Wv = (const float*)d_in[7];
    const float* bv = (const float*)d_in[8];

    const long tokens = (long)NB * SEQ;           // 8192
    const long pe = tokens * HD;                  // elems per 16 MiB buffer
    const size_t SLOT = (size_t)pe * sizeof(__bf16);   // 16 MiB
    const int ABLK = (int)(pe / 2048);            // 4096 cvt blocks per activation
    const int WBLK = WEL / 2048;                  // 512 cvt blocks per weight

    float* outCtx  = (float*)d_out;               // [4][2048][1024] f32
    float* outAttn = outCtx + tokens * HD;        // [4][2048][2048] f32
    float* colsum = outCtx;                       // 32 KB, dead until ctx GEMM
    __bf16* wb = (__bf16*)outAttn;                // bf16 weights: dead-at-start
    __bf16* Wqb = wb, *Wkb = wb + WEL, *Wvb = wb + 2 * WEL;

    const dim3 blk(256);
    hipMemsetAsync(colsum, 0, (size_t)NB * SEQ * sizeof(float), stream);

    char* w = (char*)d_ws;
    __bf16 *qp, *kp, *vT, *attnT;

    bool ebig = false;                 // E stored as bf16 in ws?
    __bf16* Ebf = nullptr;

    if (ws_size >= 6 * SLOT) {
        // [xq][xk][xv][qp][kp][vT]; after scores: E bf16 -> slots 0-1,
        // attnT -> slots 2-3 (xv+qp, both dead), vT slot 5 stays live.
        __bf16* xq = (__bf16*)w;
        __bf16* xk = (__bf16*)(w + SLOT);
        __bf16* xv = (__bf16*)(w + 2 * SLOT);
        qp = (__bf16*)(w + 3 * SLOT);
        kp = (__bf16*)(w + 4 * SLOT);
        vT = (__bf16*)(w + 5 * SLOT);
        Ebf = (__bf16*)w;
        attnT = (__bf16*)(w + 2 * SLOT);
        ebig = true;

        Cvt6 cv = {{{queries, xq, ABLK}, {keys, xk, ABLK}, {values, xv, ABLK},
                    {Wq, Wqb, WBLK}, {Wk, Wkb, WBLK}, {Wv, Wvb, WBLK}}};
        cvt_bf16<<<dim3(ABLK, 6), blk, 0, stream>>>(cv);
        Proj3 pj = {{xq, xk, xv}, {Wqb, Wkb, Wvb}, {bq, bk, bv}, {qp, kp, vT}, 4};
        gemm_proj<__bf16, __bf16><<<dim3(512 * 3), blk, 0, stream>>>(pj);
    } else if (ws_size >= 4 * SLOT) {
        // [x0][qp][kp][x1->vT]; attnT aliases x0+qp (dead after scores);
        // E stays f32 in outAttn (in-place scale_emit).
        __bf16* x0 = (__bf16*)w;
        qp = (__bf16*)(w + SLOT);
        kp = (__bf16*)(w + 2 * SLOT);
        __bf16* x1 = (__bf16*)(w + 3 * SLOT);
        vT = x1;
        attnT = (__bf16*)d_ws;

        Cvt6 cv = {{{queries, x0, ABLK}, {keys, x1, ABLK},
                    {Wq, Wqb, WBLK}, {Wk, Wkb, WBLK}, {Wv, Wvb, WBLK},
                    {nullptr, nullptr, 0}}};
        cvt_bf16<<<dim3(ABLK, 5), blk, 0, stream>>>(cv);
        Proj3 pqk = {{x0, x1, nullptr}, {Wqb, Wkb, nullptr}, {bq, bk, nullptr},
                     {qp, kp, nullptr}, 0};
        gemm_proj<__bf16, __bf16><<<dim3(512 * 2), blk, 0, stream>>>(pqk);
        Cvt6 cvv = {{{values, x0, ABLK}, {nullptr, nullptr, 0}, {nullptr, nullptr, 0},
                     {nullptr, nullptr, 0}, {nullptr, nullptr, 0}, {nullptr, nullptr, 0}}};
        cvt_bf16<<<dim3(ABLK, 1), blk, 0, stream>>>(cvv);
        Proj3 pv = {{x0, nullptr, nullptr}, {Wvb, nullptr, nullptr},
                    {bv, nullptr, nullptr}, {vT, nullptr, nullptr}, 1};
        gemm_proj<__bf16, __bf16><<<dim3(512), blk, 0, stream>>>(pv);
    } else {
        // fallback: f32-staged operands straight from inputs; [qp][kp][vT]
        qp = (__bf16*)w;
        kp = (__bf16*)(w + SLOT);
        vT = (__bf16*)(w + 2 * SLOT);
        attnT = (__bf16*)d_ws;
        Proj3 pj = {{queries, keys, values}, {Wq, Wk, Wv}, {bq, bk, bv},
                    {qp, kp, vT}, 4};
        gemm_proj<float, float><<<dim3(512 * 3), blk, 0, stream>>>(pj);
    }

    // scores + fused exp/colsum: E[b][s][t] = exp(<k_s,q_t>/32)
    // 1-D grid 544 = 4 x 136 causal blocks, XCD-remapped in-kernel
    if (ebig) {
        gemm_bt<true, false, true, __bf16><<<dim3(544), blk, 0, stream>>>(
            kp, (long)SEQ * HD, HD, qp, (long)SEQ * HD, HD,
            Ebf, (long)SEQ * SEQ, SEQ, colsum, HD, 0.03125f);
        scale_emit<__bf16><<<dim3(SEQ / 128, SEQ / 128, NB), blk, 0, stream>>>(
            Ebf, outAttn, colsum, attnT);
    } else {
        gemm_bt<true, false, true, float><<<dim3(544), blk, 0, stream>>>(
            kp, (long)SEQ * HD, HD, qp, (long)SEQ * HD, HD,
            outAttn, (long)SEQ * SEQ, SEQ, colsum, HD, 0.03125f);
        scale_emit<float><<<dim3(SEQ / 128, SEQ / 128, NB), blk, 0, stream>>>(
            outAttn, outAttn, colsum, attnT);
    }

    // context: C[b][t][h] = sum_{s<=t} attnT[t][s] * vT[h][s]
    // 1-D grid 512 = 4 x (8 n x 16 m), XCD-remapped in-kernel
    gemm_bt<false, true, false, float><<<dim3(512), blk, 0, stream>>>(
        attnT, (long)SEQ * SEQ, SEQ, vT, (long)HD * SEQ, SEQ,
        outCtx, (long)SEQ * HD, HD, nullptr, SEQ, 1.0f);
}